// Round 6
// baseline (278.575 us; speedup 1.0000x reference)
//
#include <hip/hip_runtime.h>

#define DIM   1024
#define HEADS 16
#define NSEQ  2048
#define BATCH 2

typedef unsigned short u16;
typedef unsigned long long u64;
typedef __attribute__((ext_vector_type(8))) short bf16x8;     // 8 bf16 = 4 VGPRs
typedef __attribute__((ext_vector_type(8))) _Float16 f16x8;   // 8 f16  = 4 VGPRs
typedef __attribute__((ext_vector_type(2))) __fp16 pkh2;      // cvt_pkrtz result type
typedef __attribute__((ext_vector_type(4))) float f32x4;
typedef __attribute__((ext_vector_type(16))) float f32x16;

__device__ __forceinline__ u16 f2b(float f) {
  union { float f; unsigned u; } v; v.f = f;
  unsigned r = (v.u + 0x7fffu + ((v.u >> 16) & 1u)) >> 16;  // RNE
  return (u16)r;
}

__device__ __forceinline__ u16 f2h(float f) {
  _Float16 h = (_Float16)f;                                 // v_cvt_f16_f32 (RNE)
  return __builtin_bit_cast(u16, h);
}

// async global->LDS, 16B per lane; LDS dest is wave-uniform base + lane*16
__device__ __forceinline__ void g2l16(const u16* g, u16* l) {
  __builtin_amdgcn_global_load_lds(
      (const __attribute__((address_space(1))) void*)g,
      (__attribute__((address_space(3))) void*)l, 16, 0, 0);
}

// ---------------------------------------------------------------- fp32 -> bf16
// elements with flat4-index < sc4 are scaled by s (folds softmax scale*log2e
// into the Q rows of w_qkv so exp2 args come out of QK^T free)
__global__ void cvt_bf16(const float* __restrict__ src, u16* __restrict__ dst,
                         int n4, int sc4, float s) {
  int i = blockIdx.x * blockDim.x + threadIdx.x;
  if (i < n4) {
    float4 f = ((const float4*)src)[i];
    float m = (i < sc4) ? s : 1.0f;
    union { u16 s[4]; u64 ll; } o;
    o.s[0] = f2b(f.x * m); o.s[1] = f2b(f.y * m);
    o.s[2] = f2b(f.z * m); o.s[3] = f2b(f.w * m);
    ((u64*)dst)[i] = o.ll;
  }
}

// ------------------------------------------------- C = A[M,K] @ Bt[N,K]^T (+bias)
// mode 0: f32 out + bias; mode 1: bf16 out
__global__ __launch_bounds__(256, 2)
void gemm_bt(const u16* __restrict__ A, const u16* __restrict__ Bt,
             void* __restrict__ C, const float* __restrict__ bias,
             int M, int Nc, int K, int mode) {
  __shared__ u16 As[128 * 64];
  __shared__ u16 Bs[128 * 64];
  const int tid  = threadIdx.x;
  const int wave = tid >> 6, lane = tid & 63;
  const int l15  = lane & 15, quad = lane >> 4;
  const int m0 = blockIdx.y * 128, n0 = blockIdx.x * 128;
  const int wm = (wave >> 1) * 64, wn = (wave & 1) * 64;
  const int rb = wave * 32;

  f32x4 acc[4][4] = {};

  for (int kt = 0; kt < K; kt += 64) {
#pragma unroll
    for (int c = 0; c < 4; ++c) {
      int r  = rb + c * 8 + (lane >> 3);
      int ck = (lane & 7) ^ (r & 7);
      g2l16(A  + (size_t)(m0 + r) * K + kt + ck * 8, &As[(rb + c * 8) * 64]);
      g2l16(Bt + (size_t)(n0 + r) * K + kt + ck * 8, &Bs[(rb + c * 8) * 64]);
    }
    __syncthreads();
#pragma unroll
    for (int ks = 0; ks < 2; ++ks) {
      bf16x8 a[4], b[4];
      int ch = ks * 4 + quad;
#pragma unroll
      for (int i = 0; i < 4; ++i) {
        int ra  = wm + i * 16 + l15;
        a[i] = *(const bf16x8*)&As[ra * 64 + ((ch ^ (ra & 7)) << 3)];
        int rb2 = wn + i * 16 + l15;
        b[i] = *(const bf16x8*)&Bs[rb2 * 64 + ((ch ^ (rb2 & 7)) << 3)];
      }
#pragma unroll
      for (int i = 0; i < 4; ++i)
#pragma unroll
        for (int j = 0; j < 4; ++j)
          acc[i][j] = __builtin_amdgcn_mfma_f32_16x16x32_bf16(a[i], b[j], acc[i][j], 0, 0, 0);
    }
    __syncthreads();
  }

#pragma unroll
  for (int i = 0; i < 4; ++i)
#pragma unroll
    for (int j = 0; j < 4; ++j) {
      int row = m0 + wm + i * 16 + quad * 4;
      int col = n0 + wn + j * 16 + l15;
#pragma unroll
      for (int r = 0; r < 4; ++r) {
        float v = acc[i][j][r];
        if (mode == 0) ((float*)C)[(size_t)(row + r) * Nc + col] = v + bias[col];
        else ((u16*)C)[(size_t)(row + r) * Nc + col] = f2b(v);
      }
    }
}

// ------------------------------------------ V transpose: qkv V-third -> V^T f16
// vt[(b*16+h)*64 + d][j] = f16(V[b][j][h*64+d]).  grid (B*H, N/128), 256 thr.
__global__ __launch_bounds__(256)
void vt_kernel(const u16* __restrict__ qkv, u16* __restrict__ vt) {
  __shared__ u16 T[64][136];                       // [d][j], padded
  const int tid = threadIdx.x;
  const int bh = blockIdx.x, b = bh >> 4, h = bh & 15;
  const int j0 = blockIdx.y * 128;
  const u16* src = qkv + (size_t)b * NSEQ * 3072 + 2 * DIM + h * 64;
#pragma unroll
  for (int p = 0; p < 8; ++p) {
    int jl = p * 16 + (tid >> 4);
    int d0 = (tid & 15) * 4;
    u64 v = *(const u64*)&src[(size_t)(j0 + jl) * 3072 + d0];
#pragma unroll
    for (int e = 0; e < 4; ++e) {
      unsigned bf = (unsigned)((v >> (16 * e)) & 0xFFFFu) << 16;
      T[d0 + e][jl] = f2h(__builtin_bit_cast(float, bf));
    }
  }
  __syncthreads();
  const int d = tid >> 2, g = tid & 3;
  u16* dst = vt + ((size_t)bh * 64 + d) * NSEQ + j0 + g * 32;
#pragma unroll
  for (int c = 0; c < 4; ++c)
    *(uint4*)&dst[c * 8] = *(const uint4*)&T[d][g * 32 + c * 8];
}

// --------------------------------------------------- flash attention v5
// 32x32x16 swapped-operand (S^T = K Q^T), lane owns q = lane&31.
// Fixed-max softmax (m=0; scale*log2e folded into Q weights -> raw exp2 args).
// K: LDS double-buffered via global_load_lds (shared by all 4 waves).
// V: read DIRECTLY from pre-transposed global V^T (f16) — PV A-fragment j-order
//    j = 16f + 4h + (jj&3) + 8*(jj>>2) makes each fragment two contiguous u64
//    loads. No V LDS traffic at all. P packed with v_cvt_pkrtz (no shfl).
// grid: (B*H, N/128), 256 threads, LDS 32 KB.
__global__ __launch_bounds__(256, 2)
void attn(const u16* __restrict__ qkv, const u16* __restrict__ vt,
          u16* __restrict__ outp) {
  __shared__ u16 Ks[2][128 * 64];    // K tile / Q staging, chunk-swizzle c^(row&7)
  const int tid  = threadIdx.x;
  const int wave = tid >> 6, lane = tid & 63;
  const int l31  = lane & 31, h = lane >> 5;
  const int bh = blockIdx.x, b = bh >> 4, hd = bh & 15;
  const int q0 = blockIdx.y * 128;
  const u16* base = qkv + (size_t)b * NSEQ * 3072;
  const int qoff = hd * 64, koff = DIM + hd * 64;
  const u16* vrow0 = vt + ((size_t)bh * 64 + l31) * NSEQ;        // d = l31
  const u16* vrow1 = vrow0 + (size_t)32 * NSEQ;                  // d = 32+l31

  union VF { u64 d[2]; f16x8 v; };
  union PA { unsigned w[4]; f16x8 f; };

  // ---- stage Q (128 rows) into Ks[0], pull B-fragments
#pragma unroll
  for (int c = 0; c < 4; ++c) {
    int bse = wave * 32 + c * 8;
    g2l16(base + (size_t)(q0 + bse + (lane >> 3)) * 3072 + qoff + (((lane & 7) ^ ((lane >> 3) & 7)) << 3),
          &Ks[0][bse * 64]);
  }
  __syncthreads();
  bf16x8 qf[4];
  {
    int qr = wave * 32 + l31;
#pragma unroll
    for (int kd = 0; kd < 4; ++kd)
      qf[kd] = *(const bf16x8*)&Ks[0][qr * 64 + (((kd * 2 + h) ^ (qr & 7)) << 3)];
  }
  __syncthreads();

  // ---- stage K tile 0
#pragma unroll
  for (int c = 0; c < 4; ++c) {
    int bse = wave * 32 + c * 8;
    g2l16(base + (size_t)(bse + (lane >> 3)) * 3072 + koff + (((lane & 7) ^ ((lane >> 3) & 7)) << 3),
          &Ks[0][bse * 64]);
  }
  __syncthreads();

  float lrun = 0.0f;
  f32x16 oacc[2] = {};

  for (int t = 0; t < 16; ++t) {
    const int pbuf = t & 1;
    if (t < 15) {
      const int j0n = (t + 1) * 128;
#pragma unroll
      for (int c = 0; c < 4; ++c) {
        int bse = wave * 32 + c * 8;
        g2l16(base + (size_t)(j0n + bse + (lane >> 3)) * 3072 + koff + (((lane & 7) ^ ((lane >> 3) & 7)) << 3),
              &Ks[pbuf ^ 1][bse * 64]);
      }
    }

    // ---- S^T = K Q^T in two j-halves; exp2 + pack per half (small reg footprint)
    PA pa[8];
#pragma unroll
    for (int half = 0; half < 2; ++half) {
      f32x16 s0 = {}, s1 = {};
      const int kr0 = half * 64 + l31, kr1 = kr0 + 32;
#pragma unroll
      for (int kd = 0; kd < 4; ++kd) {
        int ch = kd * 2 + h;
        bf16x8 kb0 = *(const bf16x8*)&Ks[pbuf][kr0 * 64 + ((ch ^ (kr0 & 7)) << 3)];
        bf16x8 kb1 = *(const bf16x8*)&Ks[pbuf][kr1 * 64 + ((ch ^ (kr1 & 7)) << 3)];
        s0 = __builtin_amdgcn_mfma_f32_32x32x16_bf16(kb0, qf[kd], s0, 0, 0, 0);
        s1 = __builtin_amdgcn_mfma_f32_32x32x16_bf16(kb1, qf[kd], s1, 0, 0, 0);
      }
#pragma unroll
      for (int u = 0; u < 2; ++u) {
        const f32x16& su = u ? s1 : s0;
        f32x16 p;
#pragma unroll
        for (int r = 0; r < 16; ++r) p[r] = __builtin_amdgcn_exp2f(su[r]);
        float a0 = (p[0] + p[1]) + (p[2] + p[3]);
        float a1 = (p[4] + p[5]) + (p[6] + p[7]);
        float a2 = (p[8] + p[9]) + (p[10] + p[11]);
        float a3 = (p[12] + p[13]) + (p[14] + p[15]);
        lrun += (a0 + a1) + (a2 + a3);
#pragma unroll
        for (int ks2 = 0; ks2 < 2; ++ks2)
#pragma unroll
          for (int i = 0; i < 4; ++i) {
            pkh2 t2 = __builtin_amdgcn_cvt_pkrtz(p[8 * ks2 + 2 * i], p[8 * ks2 + 2 * i + 1]);
            pa[4 * half + 2 * u + ks2].w[i] = __builtin_bit_cast(unsigned, t2);
          }
      }
    }

    // ---- O += P V : V fragments straight from global V^T
    const int j0 = t * 128;
#pragma unroll
    for (int f = 0; f < 8; ++f) {
      const int off = j0 + 16 * f + 4 * h;
      VF v0, v1;
      v0.d[0] = *(const u64*)&vrow0[off];
      v0.d[1] = *(const u64*)&vrow0[off + 8];
      v1.d[0] = *(const u64*)&vrow1[off];
      v1.d[1] = *(const u64*)&vrow1[off + 8];
      oacc[0] = __builtin_amdgcn_mfma_f32_32x32x16_f16(pa[f].f, v0.v, oacc[0], 0, 0, 0);
      oacc[1] = __builtin_amdgcn_mfma_f32_32x32x16_f16(pa[f].f, v1.v, oacc[1], 0, 0, 0);
    }
    __syncthreads();   // Ks[pbuf] reads done; g2l into Ks[pbuf^1] drained
  }

  // ---- epilogue
  float linv = 1.0f / (lrun + __shfl_xor(lrun, 32, 64));
#pragma unroll
  for (int r = 0; r < 16; ++r) {
    int rowloc = (r & 3) + 8 * (r >> 2) + 4 * h;
    float lb = __shfl(linv, rowloc, 64);
    int row = q0 + wave * 32 + rowloc;
#pragma unroll
    for (int nd = 0; nd < 2; ++nd)
      outp[((size_t)b * NSEQ + row) * DIM + hd * 64 + nd * 32 + l31] = f2b(oacc[nd][r] * lb);
  }
}

extern "C" void kernel_launch(void* const* d_in, const int* in_sizes, int n_in,
                              void* d_out, int out_size, void* d_ws, size_t ws_size,
                              hipStream_t stream) {
  const float* x     = (const float*)d_in[0];
  const float* w_qkv = (const float*)d_in[1];
  const float* w_out = (const float*)d_in[2];
  const float* b_out = (const float*)d_in[3];
  float* outp = (float*)d_out;

  u16* xb    = (u16*)d_ws;                        // 4096*1024
  u16* wqkvb = xb    + (size_t)4096 * 1024;       // 3072*1024
  u16* woutb = wqkvb + (size_t)3072 * 1024;       // 1024*1024
  u16* qkvb  = woutb + (size_t)1024 * 1024;       // 4096*3072 bf16
  u16* attnb = qkvb  + (size_t)4096 * 3072;       // 4096*1024
  u16* vtb   = attnb + (size_t)4096 * 1024;       // 32*64*2048 f16 (V^T)

  const float C2 = 0.03125f * 1.44269504088896340736f;  // dim^-0.5 * log2(e)

  cvt_bf16<<<4096 * 1024 / 4 / 256, 256, 0, stream>>>(x,     xb,    4096 * 1024 / 4, 0, 1.0f);
  cvt_bf16<<<3072 * 1024 / 4 / 256, 256, 0, stream>>>(w_qkv, wqkvb, 3072 * 1024 / 4,
                                                      1024 * 1024 / 4, C2);
  cvt_bf16<<<1024 * 1024 / 4 / 256, 256, 0, stream>>>(w_out, woutb, 1024 * 1024 / 4, 0, 1.0f);

  gemm_bt<<<dim3(24, 32), 256, 0, stream>>>(xb, wqkvb, qkvb, nullptr, 4096, 3072, 1024, 1);
  vt_kernel<<<dim3(32, 16), 256, 0, stream>>>(qkvb, vtb);
  attn<<<dim3(32, 16), 256, 0, stream>>>(qkvb, vtb, attnb);
  gemm_bt<<<dim3(8, 32), 256, 0, stream>>>(attnb, woutb, outp, b_out, 4096, 1024, 1024, 0);
}

// Round 7
// 220.360 us; speedup vs baseline: 1.2642x; 1.2642x over previous
//
#include <hip/hip_runtime.h>

#define DIM   1024
#define HEADS 16
#define NSEQ  2048
#define BATCH 2

typedef unsigned short u16;
typedef unsigned long long u64;
typedef __attribute__((ext_vector_type(8))) short bf16x8;     // 8 bf16 = 4 VGPRs
typedef __attribute__((ext_vector_type(8))) _Float16 f16x8;   // 8 f16  = 4 VGPRs
typedef __attribute__((ext_vector_type(2))) __fp16 pkh2;      // cvt_pkrtz result type
typedef __attribute__((ext_vector_type(4))) float f32x4;
typedef __attribute__((ext_vector_type(16))) float f32x16;

__device__ __forceinline__ u16 f2b(float f) {
  union { float f; unsigned u; } v; v.f = f;
  unsigned r = (v.u + 0x7fffu + ((v.u >> 16) & 1u)) >> 16;  // RNE
  return (u16)r;
}

__device__ __forceinline__ u16 f2h(float f) {
  _Float16 h = (_Float16)f;                                 // v_cvt_f16_f32 (RNE)
  return __builtin_bit_cast(u16, h);
}

__device__ __forceinline__ float h2f(u16 h) {
  return (float)__builtin_bit_cast(_Float16, h);
}

// async global->LDS, 16B per lane; LDS dest is wave-uniform base + lane*16
__device__ __forceinline__ void g2l16(const u16* g, u16* l) {
  __builtin_amdgcn_global_load_lds(
      (const __attribute__((address_space(1))) void*)g,
      (__attribute__((address_space(3))) void*)l, 16, 0, 0);
}

// ---------------------------------------------------------------- fp32 -> bf16
// elements with flat4-index < sc4 are scaled by s (folds softmax scale*log2e
// into the Q rows of w_qkv so exp2 args come out of QK^T free)
__global__ void cvt_bf16(const float* __restrict__ src, u16* __restrict__ dst,
                         int n4, int sc4, float s) {
  int i = blockIdx.x * blockDim.x + threadIdx.x;
  if (i < n4) {
    float4 f = ((const float4*)src)[i];
    float m = (i < sc4) ? s : 1.0f;
    union { u16 s[4]; u64 ll; } o;
    o.s[0] = f2b(f.x * m); o.s[1] = f2b(f.y * m);
    o.s[2] = f2b(f.z * m); o.s[3] = f2b(f.w * m);
    ((u64*)dst)[i] = o.ll;
  }
}

// ------------------------------------------------- C = A[M,K] @ Bt[N,K]^T (+bias)
// mode 0: f32 out + bias; mode 1: bf16 out
__global__ __launch_bounds__(256, 2)
void gemm_bt(const u16* __restrict__ A, const u16* __restrict__ Bt,
             void* __restrict__ C, const float* __restrict__ bias,
             int M, int Nc, int K, int mode) {
  __shared__ u16 As[128 * 64];
  __shared__ u16 Bs[128 * 64];
  const int tid  = threadIdx.x;
  const int wave = tid >> 6, lane = tid & 63;
  const int l15  = lane & 15, quad = lane >> 4;
  const int m0 = blockIdx.y * 128, n0 = blockIdx.x * 128;
  const int wm = (wave >> 1) * 64, wn = (wave & 1) * 64;
  const int rb = wave * 32;

  f32x4 acc[4][4] = {};

  for (int kt = 0; kt < K; kt += 64) {
#pragma unroll
    for (int c = 0; c < 4; ++c) {
      int r  = rb + c * 8 + (lane >> 3);
      int ck = (lane & 7) ^ (r & 7);
      g2l16(A  + (size_t)(m0 + r) * K + kt + ck * 8, &As[(rb + c * 8) * 64]);
      g2l16(Bt + (size_t)(n0 + r) * K + kt + ck * 8, &Bs[(rb + c * 8) * 64]);
    }
    __syncthreads();
#pragma unroll
    for (int ks = 0; ks < 2; ++ks) {
      bf16x8 a[4], b[4];
      int ch = ks * 4 + quad;
#pragma unroll
      for (int i = 0; i < 4; ++i) {
        int ra  = wm + i * 16 + l15;
        a[i] = *(const bf16x8*)&As[ra * 64 + ((ch ^ (ra & 7)) << 3)];
        int rb2 = wn + i * 16 + l15;
        b[i] = *(const bf16x8*)&Bs[rb2 * 64 + ((ch ^ (rb2 & 7)) << 3)];
      }
#pragma unroll
      for (int i = 0; i < 4; ++i)
#pragma unroll
        for (int j = 0; j < 4; ++j)
          acc[i][j] = __builtin_amdgcn_mfma_f32_16x16x32_bf16(a[i], b[j], acc[i][j], 0, 0, 0);
    }
    __syncthreads();
  }

#pragma unroll
  for (int i = 0; i < 4; ++i)
#pragma unroll
    for (int j = 0; j < 4; ++j) {
      int row = m0 + wm + i * 16 + quad * 4;
      int col = n0 + wn + j * 16 + l15;
#pragma unroll
      for (int r = 0; r < 4; ++r) {
        float v = acc[i][j][r];
        if (mode == 0) ((float*)C)[(size_t)(row + r) * Nc + col] = v + bias[col];
        else ((u16*)C)[(size_t)(row + r) * Nc + col] = f2b(v);
      }
    }
}

// -------------------------- V transpose into PV-fragment layout (f16)
// Output: 1KB chunks indexed ((bh*16+t)*8+f)*2+nd; within a chunk lane
// (h=lane>>5, l31=lane&31) holds 16B = V^T[d=nd*32+l31][t*128 + jbase + {0..3,8..11}]
// where jbase = (f>>2)*64 + ((f>>1)&1)*32 + (f&1)*16 + 4*h.
// grid (B*H, 16), 256 threads.
__global__ __launch_bounds__(256)
void vt_kernel(const u16* __restrict__ qkv, u16* __restrict__ vt) {
  __shared__ u16 T[64][132];                       // [d][j] f16, pad 132
  const int tid = threadIdx.x;
  const int bh = blockIdx.x, b = bh >> 4, hd = bh & 15;
  const int tt = blockIdx.y;
  const int j0 = tt * 128;
  const u16* src = qkv + (size_t)b * NSEQ * 3072 + 2 * DIM + hd * 64;
#pragma unroll
  for (int p = 0; p < 8; ++p) {
    int jl = p * 16 + (tid >> 4);
    int d0 = (tid & 15) * 4;
    u64 v = *(const u64*)&src[(size_t)(j0 + jl) * 3072 + d0];
#pragma unroll
    for (int e = 0; e < 4; ++e) {
      unsigned bf = (unsigned)((v >> (16 * e)) & 0xFFFFu) << 16;
      T[d0 + e][jl] = f2h(__builtin_bit_cast(float, bf));
    }
  }
  __syncthreads();
  const int w = tid >> 6, lane = tid & 63;
  const int hh = lane >> 5, l31 = lane & 31;
#pragma unroll
  for (int fi = 0; fi < 2; ++fi) {
    int f = w + fi * 4;
    int jbase = (f >> 2) * 64 + ((f >> 1) & 1) * 32 + (f & 1) * 16 + 4 * hh;
#pragma unroll
    for (int nd = 0; nd < 2; ++nd) {
      int d = nd * 32 + l31;
      u64 lo = *(const u64*)&T[d][jbase];
      u64 hi = *(const u64*)&T[d][jbase + 8];
      u64* dst = (u64*)(vt + ((((size_t)bh * 16 + tt) * 8 + f) * 2 + nd) * 512 + lane * 8);
      dst[0] = lo; dst[1] = hi;
    }
  }
}

// --------------------------------------------------- flash attention v6
// 32x32x16 swapped-operand (S^T = K Q^T), lane owns q = lane&31.
// Fixed-max softmax (m=0; scale*log2e folded into Q weights). j-split x2:
// block handles 8 of 16 j-tiles, writes RAW O partial (f16) + l partial (f32);
// combine kernel sums+normalizes. K: LDS double-buffered (32 KB). V: coalesced
// dwordx4 fragment loads from pre-laid-out global V^T. 4 blocks/CU.
// grid: (B*H, N/128, 2), 256 threads.
__global__ __launch_bounds__(256, 4)
void attn(const u16* __restrict__ qkv, const u16* __restrict__ vt,
          u16* __restrict__ opart, float* __restrict__ lpart) {
  __shared__ u16 Ks[2][128 * 64];    // K tile / Q staging, chunk-swizzle c^(row&7)
  const int tid  = threadIdx.x;
  const int wave = tid >> 6, lane = tid & 63;
  const int l31  = lane & 31, h = lane >> 5;
  const int bh = blockIdx.x, b = bh >> 4;
  const int qt = blockIdx.y, q0 = qt * 128;
  const int js = blockIdx.z;
  const u16* base = qkv + (size_t)b * NSEQ * 3072;
  const int qoff = (bh & 15) * 64, koff = DIM + (bh & 15) * 64;
  const u16* vbase = vt + ((size_t)bh * 16 + js * 8) * 8 * 2 * 512 + lane * 8;

  union VF { uint4 q; f16x8 v; };
  union PA { unsigned w[4]; f16x8 f; };

  // ---- stage Q (128 rows) into Ks[0], pull B-fragments
#pragma unroll
  for (int c = 0; c < 4; ++c) {
    int bse = wave * 32 + c * 8;
    g2l16(base + (size_t)(q0 + bse + (lane >> 3)) * 3072 + qoff + (((lane & 7) ^ ((lane >> 3) & 7)) << 3),
          &Ks[0][bse * 64]);
  }
  __syncthreads();
  bf16x8 qf[4];
  {
    int qr = wave * 32 + l31;
#pragma unroll
    for (int kd = 0; kd < 4; ++kd)
      qf[kd] = *(const bf16x8*)&Ks[0][qr * 64 + (((kd * 2 + h) ^ (qr & 7)) << 3)];
  }
  __syncthreads();

  // ---- stage K tile 0 (j-tile js*8)
#pragma unroll
  for (int c = 0; c < 4; ++c) {
    int bse = wave * 32 + c * 8;
    g2l16(base + (size_t)(js * 1024 + bse + (lane >> 3)) * 3072 + koff + (((lane & 7) ^ ((lane >> 3) & 7)) << 3),
          &Ks[0][bse * 64]);
  }
  __syncthreads();

  float lrun = 0.0f;
  f32x16 oacc[2] = {};

  for (int t = 0; t < 8; ++t) {
    const int pbuf = t & 1;
    if (t < 7) {
      const int j0n = (js * 8 + t + 1) * 128;
#pragma unroll
      for (int c = 0; c < 4; ++c) {
        int bse = wave * 32 + c * 8;
        g2l16(base + (size_t)(j0n + bse + (lane >> 3)) * 3072 + koff + (((lane & 7) ^ ((lane >> 3) & 7)) << 3),
              &Ks[pbuf ^ 1][bse * 64]);
      }
    }

    // ---- S^T = K Q^T in two j-halves; exp2 + pack per half
    PA pa[8];
#pragma unroll
    for (int half = 0; half < 2; ++half) {
      f32x16 s0 = {}, s1 = {};
      const int kr0 = half * 64 + l31, kr1 = kr0 + 32;
#pragma unroll
      for (int kd = 0; kd < 4; ++kd) {
        int ch = kd * 2 + h;
        bf16x8 kb0 = *(const bf16x8*)&Ks[pbuf][kr0 * 64 + ((ch ^ (kr0 & 7)) << 3)];
        bf16x8 kb1 = *(const bf16x8*)&Ks[pbuf][kr1 * 64 + ((ch ^ (kr1 & 7)) << 3)];
        s0 = __builtin_amdgcn_mfma_f32_32x32x16_bf16(kb0, qf[kd], s0, 0, 0, 0);
        s1 = __builtin_amdgcn_mfma_f32_32x32x16_bf16(kb1, qf[kd], s1, 0, 0, 0);
      }
#pragma unroll
      for (int u = 0; u < 2; ++u) {
        const f32x16& su = u ? s1 : s0;
        f32x16 p;
#pragma unroll
        for (int r = 0; r < 16; ++r) p[r] = __builtin_amdgcn_exp2f(su[r]);
        float a0 = (p[0] + p[1]) + (p[2] + p[3]);
        float a1 = (p[4] + p[5]) + (p[6] + p[7]);
        float a2 = (p[8] + p[9]) + (p[10] + p[11]);
        float a3 = (p[12] + p[13]) + (p[14] + p[15]);
        lrun += (a0 + a1) + (a2 + a3);
#pragma unroll
        for (int ks2 = 0; ks2 < 2; ++ks2)
#pragma unroll
          for (int i = 0; i < 4; ++i) {
            pkh2 t2 = __builtin_amdgcn_cvt_pkrtz(p[8 * ks2 + 2 * i], p[8 * ks2 + 2 * i + 1]);
            pa[4 * half + 2 * u + ks2].w[i] = __builtin_bit_cast(unsigned, t2);
          }
      }
    }

    // ---- O += P V : coalesced dwordx4 fragment loads from global V^T
    const u16* vtile = vbase + (size_t)t * 16 * 512;
#pragma unroll
    for (int f = 0; f < 8; ++f) {
      VF v0, v1;
      v0.q = *(const uint4*)(vtile + (f * 2 + 0) * 512);
      v1.q = *(const uint4*)(vtile + (f * 2 + 1) * 512);
      oacc[0] = __builtin_amdgcn_mfma_f32_32x32x16_f16(pa[f].f, v0.v, oacc[0], 0, 0, 0);
      oacc[1] = __builtin_amdgcn_mfma_f32_32x32x16_f16(pa[f].f, v1.v, oacc[1], 0, 0, 0);
    }
    __syncthreads();   // Ks[pbuf] reads done; g2l into Ks[pbuf^1] drained
  }

  // ---- epilogue: store RAW partials (no normalization)
  const size_t pb = ((size_t)js * 32 + bh) * 16 + qt;       // partial-tile index
  u16* op = opart + pb * 128 * 64;
  float lsum = lrun + __shfl_xor(lrun, 32, 64);
  if (h == 0) lpart[pb * 128 + wave * 32 + l31] = lsum;
#pragma unroll
  for (int r = 0; r < 16; ++r) {
    int rowloc = (r & 3) + 8 * (r >> 2) + 4 * h;
    int q = wave * 32 + rowloc;
#pragma unroll
    for (int nd = 0; nd < 2; ++nd)
      op[(size_t)q * 64 + nd * 32 + l31] = f2h(oacc[nd][r]);
  }
}

// ------------------------------------------ combine: (O0+O1)/(l0+l1) -> bf16
// grid (B*H, 16), 256 threads.
__global__ __launch_bounds__(256)
void combine(const u16* __restrict__ opart, const float* __restrict__ lpart,
             u16* __restrict__ outp) {
  const int tid = threadIdx.x;
  const int bh = blockIdx.x, b = bh >> 4, hd = bh & 15;
  const int qt = blockIdx.y;
  const size_t pb0 = (size_t)bh * 16 + qt;
  const size_t pb1 = pb0 + 512;
  const u16* o0 = opart + pb0 * 128 * 64;
  const u16* o1 = opart + pb1 * 128 * 64;
  const float* l0 = lpart + pb0 * 128;
  const float* l1 = lpart + pb1 * 128;
#pragma unroll
  for (int c = 0; c < 4; ++c) {
    int chunk = tid + c * 256;            // 0..1023
    int q = chunk >> 3, d0 = (chunk & 7) * 8;
    float inv = 1.0f / (l0[q] + l1[q]);
    union { uint4 v; u16 s[8]; } a, bb, o;
    a.v  = *(const uint4*)&o0[(size_t)q * 64 + d0];
    bb.v = *(const uint4*)&o1[(size_t)q * 64 + d0];
#pragma unroll
    for (int e = 0; e < 8; ++e)
      o.s[e] = f2b((h2f(a.s[e]) + h2f(bb.s[e])) * inv);
    *(uint4*)&outp[((size_t)b * NSEQ + qt * 128 + q) * DIM + hd * 64 + d0] = o.v;
  }
}

extern "C" void kernel_launch(void* const* d_in, const int* in_sizes, int n_in,
                              void* d_out, int out_size, void* d_ws, size_t ws_size,
                              hipStream_t stream) {
  const float* x     = (const float*)d_in[0];
  const float* w_qkv = (const float*)d_in[1];
  const float* w_out = (const float*)d_in[2];
  const float* b_out = (const float*)d_in[3];
  float* outp = (float*)d_out;

  u16*   xb    = (u16*)d_ws;                        // 4096*1024 bf16
  u16*   wqkvb = xb    + (size_t)4096 * 1024;       // 3072*1024 bf16
  u16*   woutb = wqkvb + (size_t)3072 * 1024;       // 1024*1024 bf16
  u16*   qkvb  = woutb + (size_t)1024 * 1024;       // 4096*3072 bf16
  u16*   attnb = qkvb  + (size_t)4096 * 3072;       // 4096*1024 bf16
  u16*   vtb   = attnb + (size_t)4096 * 1024;       // 4M f16 (V^T fragments)
  u16*   opart = vtb   + (size_t)4096 * 1024;       // 2*512*128*64 f16
  float* lpart = (float*)(opart + (size_t)2 * 512 * 128 * 64);  // 2*512*128 f32

  const float C2 = 0.03125f * 1.44269504088896340736f;  // dim^-0.5 * log2(e)

  cvt_bf16<<<4096 * 1024 / 4 / 256, 256, 0, stream>>>(x,     xb,    4096 * 1024 / 4, 0, 1.0f);
  cvt_bf16<<<3072 * 1024 / 4 / 256, 256, 0, stream>>>(w_qkv, wqkvb, 3072 * 1024 / 4,
                                                      1024 * 1024 / 4, C2);
  cvt_bf16<<<1024 * 1024 / 4 / 256, 256, 0, stream>>>(w_out, woutb, 1024 * 1024 / 4, 0, 1.0f);

  gemm_bt<<<dim3(24, 32), 256, 0, stream>>>(xb, wqkvb, qkvb, nullptr, 4096, 3072, 1024, 1);
  vt_kernel<<<dim3(32, 16), 256, 0, stream>>>(qkvb, vtb);
  attn<<<dim3(32, 16, 2), 256, 0, stream>>>(qkvb, vtb, opart, lpart);
  combine<<<dim3(32, 16), 256, 0, stream>>>(opart, lpart, attnb);
  gemm_bt<<<dim3(8, 32), 256, 0, stream>>>(attnb, woutb, outp, b_out, 4096, 1024, 1024, 0);
}

// Round 8
// 206.242 us; speedup vs baseline: 1.3507x; 1.0685x over previous
//
#include <hip/hip_runtime.h>

#define DIM   1024
#define HEADS 16
#define NSEQ  2048
#define BATCH 2

typedef unsigned short u16;
typedef unsigned long long u64;
typedef __attribute__((ext_vector_type(8))) short bf16x8;     // 8 bf16 = 4 VGPRs
typedef __attribute__((ext_vector_type(8))) _Float16 f16x8;   // 8 f16  = 4 VGPRs
typedef __attribute__((ext_vector_type(2))) __fp16 pkh2;      // cvt_pkrtz result type
typedef __attribute__((ext_vector_type(4))) float f32x4;
typedef __attribute__((ext_vector_type(16))) float f32x16;

__device__ __forceinline__ u16 f2b(float f) {
  union { float f; unsigned u; } v; v.f = f;
  unsigned r = (v.u + 0x7fffu + ((v.u >> 16) & 1u)) >> 16;  // RNE
  return (u16)r;
}

__device__ __forceinline__ u16 f2h(float f) {
  _Float16 h = (_Float16)f;                                 // v_cvt_f16_f32 (RNE)
  return __builtin_bit_cast(u16, h);
}

__device__ __forceinline__ float h2f(u16 h) {
  return (float)__builtin_bit_cast(_Float16, h);
}

// async global->LDS, 16B per lane; LDS dest is wave-uniform base + lane*16
__device__ __forceinline__ void g2l16(const u16* g, u16* l) {
  __builtin_amdgcn_global_load_lds(
      (const __attribute__((address_space(1))) void*)g,
      (__attribute__((address_space(3))) void*)l, 16, 0, 0);
}

// ---------------------------------------------------------------- fp32 -> bf16
// elements with flat4-index < sc4 are scaled by s (folds softmax scale*log2e
// into the Q rows of w_qkv so exp2 args come out of QK^T free)
__global__ void cvt_bf16(const float* __restrict__ src, u16* __restrict__ dst,
                         int n4, int sc4, float s) {
  int i = blockIdx.x * blockDim.x + threadIdx.x;
  if (i < n4) {
    float4 f = ((const float4*)src)[i];
    float m = (i < sc4) ? s : 1.0f;
    union { u16 s[4]; u64 ll; } o;
    o.s[0] = f2b(f.x * m); o.s[1] = f2b(f.y * m);
    o.s[2] = f2b(f.z * m); o.s[3] = f2b(f.w * m);
    ((u64*)dst)[i] = o.ll;
  }
}

// ------------------------------------------------- C = A[M,K] @ Bt[N,K]^T (+bias)
// mode 0: f32 out + bias; mode 1: bf16 out
__global__ __launch_bounds__(256, 2)
void gemm_bt(const u16* __restrict__ A, const u16* __restrict__ Bt,
             void* __restrict__ C, const float* __restrict__ bias,
             int M, int Nc, int K, int mode) {
  __shared__ u16 As[128 * 64];
  __shared__ u16 Bs[128 * 64];
  const int tid  = threadIdx.x;
  const int wave = tid >> 6, lane = tid & 63;
  const int l15  = lane & 15, quad = lane >> 4;
  const int m0 = blockIdx.y * 128, n0 = blockIdx.x * 128;
  const int wm = (wave >> 1) * 64, wn = (wave & 1) * 64;
  const int rb = wave * 32;

  f32x4 acc[4][4] = {};

  for (int kt = 0; kt < K; kt += 64) {
#pragma unroll
    for (int c = 0; c < 4; ++c) {
      int r  = rb + c * 8 + (lane >> 3);
      int ck = (lane & 7) ^ (r & 7);
      g2l16(A  + (size_t)(m0 + r) * K + kt + ck * 8, &As[(rb + c * 8) * 64]);
      g2l16(Bt + (size_t)(n0 + r) * K + kt + ck * 8, &Bs[(rb + c * 8) * 64]);
    }
    __syncthreads();
#pragma unroll
    for (int ks = 0; ks < 2; ++ks) {
      bf16x8 a[4], b[4];
      int ch = ks * 4 + quad;
#pragma unroll
      for (int i = 0; i < 4; ++i) {
        int ra  = wm + i * 16 + l15;
        a[i] = *(const bf16x8*)&As[ra * 64 + ((ch ^ (ra & 7)) << 3)];
        int rb2 = wn + i * 16 + l15;
        b[i] = *(const bf16x8*)&Bs[rb2 * 64 + ((ch ^ (rb2 & 7)) << 3)];
      }
#pragma unroll
      for (int i = 0; i < 4; ++i)
#pragma unroll
        for (int j = 0; j < 4; ++j)
          acc[i][j] = __builtin_amdgcn_mfma_f32_16x16x32_bf16(a[i], b[j], acc[i][j], 0, 0, 0);
    }
    __syncthreads();
  }

#pragma unroll
  for (int i = 0; i < 4; ++i)
#pragma unroll
    for (int j = 0; j < 4; ++j) {
      int row = m0 + wm + i * 16 + quad * 4;
      int col = n0 + wn + j * 16 + l15;
#pragma unroll
      for (int r = 0; r < 4; ++r) {
        float v = acc[i][j][r];
        if (mode == 0) ((float*)C)[(size_t)(row + r) * Nc + col] = v + bias[col];
        else ((u16*)C)[(size_t)(row + r) * Nc + col] = f2b(v);
      }
    }
}

// -------------------------- V transpose into PV-fragment layout (f16)
// Output: 1KB chunks indexed ((bh*16+t)*8+f)*2+nd; within a chunk lane
// (h=lane>>5, l31=lane&31) holds 16B = V^T[d=nd*32+l31][t*128 + jbase + {0..3,8..11}]
// where jbase = (f>>2)*64 + ((f>>1)&1)*32 + (f&1)*16 + 4*h.
// grid (B*H, 16), 256 threads.
__global__ __launch_bounds__(256)
void vt_kernel(const u16* __restrict__ qkv, u16* __restrict__ vt) {
  __shared__ u16 T[64][132];                       // [d][j] f16, pad 132
  const int tid = threadIdx.x;
  const int bh = blockIdx.x, b = bh >> 4, hd = bh & 15;
  const int tt = blockIdx.y;
  const int j0 = tt * 128;
  const u16* src = qkv + (size_t)b * NSEQ * 3072 + 2 * DIM + hd * 64;
#pragma unroll
  for (int p = 0; p < 8; ++p) {
    int jl = p * 16 + (tid >> 4);
    int d0 = (tid & 15) * 4;
    u64 v = *(const u64*)&src[(size_t)(j0 + jl) * 3072 + d0];
#pragma unroll
    for (int e = 0; e < 4; ++e) {
      unsigned bf = (unsigned)((v >> (16 * e)) & 0xFFFFu) << 16;
      T[d0 + e][jl] = f2h(__builtin_bit_cast(float, bf));
    }
  }
  __syncthreads();
  const int w = tid >> 6, lane = tid & 63;
  const int hh = lane >> 5, l31 = lane & 31;
#pragma unroll
  for (int fi = 0; fi < 2; ++fi) {
    int f = w + fi * 4;
    int jbase = (f >> 2) * 64 + ((f >> 1) & 1) * 32 + (f & 1) * 16 + 4 * hh;
#pragma unroll
    for (int nd = 0; nd < 2; ++nd) {
      int d = nd * 32 + l31;
      u64 lo = *(const u64*)&T[d][jbase];
      u64 hi = *(const u64*)&T[d][jbase + 8];
      u64* dst = (u64*)(vt + ((((size_t)bh * 16 + tt) * 8 + f) * 2 + nd) * 512 + lane * 8);
      dst[0] = lo; dst[1] = hi;
    }
  }
}

// --------------------------------------------------- flash attention v7
// 32x32x16 swapped-operand (S^T = K Q^T), lane owns q = lane&31.
// Fixed-max softmax (m=0; scale*log2e folded into Q weights). j-split x2 with
// raw O/l partials + combine kernel. K: LDS double-buffered via g2l.
// V: fragment-layout vt staged via g2l into 16 KB LDS buffer (per-tile),
// consumed as contiguous conflict-free ds_read_b128 — no VMEM dependence in
// the PV loop. Two barriers/tile: g2l(V(t),K(t+1)) -> QK/exp2 -> B(drain) ->
// PV -> B(free Vs). LDS 48 KB -> 3 blocks/CU.
// grid: (B*H, N/128, 2), 256 threads.
__global__ __launch_bounds__(256, 3)
void attn(const u16* __restrict__ qkv, const u16* __restrict__ vt,
          u16* __restrict__ opart, float* __restrict__ lpart) {
  __shared__ u16 Ks[2][128 * 64];    // 32 KB: K tile / Q staging, swizzle c^(row&7)
  __shared__ u16 Vs[16 * 512];       // 16 KB: V fragments (f*2+nd chunks of 1 KB)
  const int tid  = threadIdx.x;
  const int wave = tid >> 6, lane = tid & 63;
  const int l31  = lane & 31, h = lane >> 5;
  const int bh = blockIdx.x, b = bh >> 4;
  const int qt = blockIdx.y, q0 = qt * 128;
  const int js = blockIdx.z;
  const u16* base = qkv + (size_t)b * NSEQ * 3072;
  const int qoff = (bh & 15) * 64, koff = DIM + (bh & 15) * 64;
  // vt chunk base for this block's first tile (tile index tt = js*8 + t)
  const u16* vbase = vt + ((size_t)bh * 16 + js * 8) * 16 * 512;

  union PA { unsigned w[4]; f16x8 f; };

  // ---- stage Q (128 rows) into Ks[0], pull B-fragments
#pragma unroll
  for (int c = 0; c < 4; ++c) {
    int bse = wave * 32 + c * 8;
    g2l16(base + (size_t)(q0 + bse + (lane >> 3)) * 3072 + qoff + (((lane & 7) ^ ((lane >> 3) & 7)) << 3),
          &Ks[0][bse * 64]);
  }
  __syncthreads();
  bf16x8 qf[4];
  {
    int qr = wave * 32 + l31;
#pragma unroll
    for (int kd = 0; kd < 4; ++kd)
      qf[kd] = *(const bf16x8*)&Ks[0][qr * 64 + (((kd * 2 + h) ^ (qr & 7)) << 3)];
  }
  __syncthreads();

  // ---- stage K tile 0 (j-tile js*8)
#pragma unroll
  for (int c = 0; c < 4; ++c) {
    int bse = wave * 32 + c * 8;
    g2l16(base + (size_t)(js * 1024 + bse + (lane >> 3)) * 3072 + koff + (((lane & 7) ^ ((lane >> 3) & 7)) << 3),
          &Ks[0][bse * 64]);
  }
  __syncthreads();

  float lrun = 0.0f;
  f32x16 oacc[2] = {};

  for (int t = 0; t < 8; ++t) {
    const int pbuf = t & 1;

    // ---- issue async staging: V(t) -> Vs, K(t+1) -> Ks[pbuf^1]
    {
      // 16 V chunks / 4 waves = 4 g2l per wave; source lane addr = chunk + lane*16B
      const u16* vsrc = vbase + ((size_t)t * 16 + wave * 4) * 512 + lane * 8;
#pragma unroll
      for (int c = 0; c < 4; ++c)
        g2l16(vsrc + c * 512, &Vs[(wave * 4 + c) * 512]);
    }
    if (t < 7) {
      const int j0n = (js * 8 + t + 1) * 128;
#pragma unroll
      for (int c = 0; c < 4; ++c) {
        int bse = wave * 32 + c * 8;
        g2l16(base + (size_t)(j0n + bse + (lane >> 3)) * 3072 + koff + (((lane & 7) ^ ((lane >> 3) & 7)) << 3),
              &Ks[pbuf ^ 1][bse * 64]);
      }
    }

    // ---- S^T = K Q^T in two j-halves; exp2 + pack per half
    PA pa[8];
#pragma unroll
    for (int half = 0; half < 2; ++half) {
      f32x16 s0 = {}, s1 = {};
      const int kr0 = half * 64 + l31, kr1 = kr0 + 32;
#pragma unroll
      for (int kd = 0; kd < 4; ++kd) {
        int ch = kd * 2 + h;
        bf16x8 kb0 = *(const bf16x8*)&Ks[pbuf][kr0 * 64 + ((ch ^ (kr0 & 7)) << 3)];
        bf16x8 kb1 = *(const bf16x8*)&Ks[pbuf][kr1 * 64 + ((ch ^ (kr1 & 7)) << 3)];
        s0 = __builtin_amdgcn_mfma_f32_32x32x16_bf16(kb0, qf[kd], s0, 0, 0, 0);
        s1 = __builtin_amdgcn_mfma_f32_32x32x16_bf16(kb1, qf[kd], s1, 0, 0, 0);
      }
#pragma unroll
      for (int u = 0; u < 2; ++u) {
        const f32x16& su = u ? s1 : s0;
        f32x16 p;
#pragma unroll
        for (int r = 0; r < 16; ++r) p[r] = __builtin_amdgcn_exp2f(su[r]);
        float a0 = (p[0] + p[1]) + (p[2] + p[3]);
        float a1 = (p[4] + p[5]) + (p[6] + p[7]);
        float a2 = (p[8] + p[9]) + (p[10] + p[11]);
        float a3 = (p[12] + p[13]) + (p[14] + p[15]);
        lrun += (a0 + a1) + (a2 + a3);
#pragma unroll
        for (int ks2 = 0; ks2 < 2; ++ks2)
#pragma unroll
          for (int i = 0; i < 4; ++i) {
            pkh2 t2 = __builtin_amdgcn_cvt_pkrtz(p[8 * ks2 + 2 * i], p[8 * ks2 + 2 * i + 1]);
            pa[4 * half + 2 * u + ks2].w[i] = __builtin_bit_cast(unsigned, t2);
          }
      }
    }

    __syncthreads();   // drains vmcnt: V(t) and K(t+1) now resident in LDS

    // ---- O += P V : conflict-free contiguous ds_read_b128 fragment loads
#pragma unroll
    for (int f = 0; f < 8; ++f) {
      f16x8 v0 = *(const f16x8*)&Vs[(f * 2 + 0) * 512 + lane * 8];
      f16x8 v1 = *(const f16x8*)&Vs[(f * 2 + 1) * 512 + lane * 8];
      oacc[0] = __builtin_amdgcn_mfma_f32_32x32x16_f16(pa[f].f, v0, oacc[0], 0, 0, 0);
      oacc[1] = __builtin_amdgcn_mfma_f32_32x32x16_f16(pa[f].f, v1, oacc[1], 0, 0, 0);
    }

    __syncthreads();   // PV reads of Vs complete -> next iter may overwrite Vs
  }

  // ---- epilogue: store RAW partials (no normalization)
  const size_t pb = ((size_t)js * 32 + bh) * 16 + qt;       // partial-tile index
  u16* op = opart + pb * 128 * 64;
  float lsum = lrun + __shfl_xor(lrun, 32, 64);
  if (h == 0) lpart[pb * 128 + wave * 32 + l31] = lsum;
#pragma unroll
  for (int r = 0; r < 16; ++r) {
    int rowloc = (r & 3) + 8 * (r >> 2) + 4 * h;
    int q = wave * 32 + rowloc;
#pragma unroll
    for (int nd = 0; nd < 2; ++nd)
      op[(size_t)q * 64 + nd * 32 + l31] = f2h(oacc[nd][r]);
  }
}

// ------------------------------------------ combine: (O0+O1)/(l0+l1) -> bf16
// grid (B*H, 16), 256 threads.
__global__ __launch_bounds__(256)
void combine(const u16* __restrict__ opart, const float* __restrict__ lpart,
             u16* __restrict__ outp) {
  const int tid = threadIdx.x;
  const int bh = blockIdx.x, b = bh >> 4, hd = bh & 15;
  const int qt = blockIdx.y;
  const size_t pb0 = (size_t)bh * 16 + qt;
  const size_t pb1 = pb0 + 512;
  const u16* o0 = opart + pb0 * 128 * 64;
  const u16* o1 = opart + pb1 * 128 * 64;
  const float* l0 = lpart + pb0 * 128;
  const float* l1 = lpart + pb1 * 128;
#pragma unroll
  for (int c = 0; c < 4; ++c) {
    int chunk = tid + c * 256;            // 0..1023
    int q = chunk >> 3, d0 = (chunk & 7) * 8;
    float inv = 1.0f / (l0[q] + l1[q]);
    union { uint4 v; u16 s[8]; } a, bb, o;
    a.v  = *(const uint4*)&o0[(size_t)q * 64 + d0];
    bb.v = *(const uint4*)&o1[(size_t)q * 64 + d0];
#pragma unroll
    for (int e = 0; e < 8; ++e)
      o.s[e] = f2b((h2f(a.s[e]) + h2f(bb.s[e])) * inv);
    *(uint4*)&outp[((size_t)b * NSEQ + qt * 128 + q) * DIM + hd * 64 + d0] = o.v;
  }
}

extern "C" void kernel_launch(void* const* d_in, const int* in_sizes, int n_in,
                              void* d_out, int out_size, void* d_ws, size_t ws_size,
                              hipStream_t stream) {
  const float* x     = (const float*)d_in[0];
  const float* w_qkv = (const float*)d_in[1];
  const float* w_out = (const float*)d_in[2];
  const float* b_out = (const float*)d_in[3];
  float* outp = (float*)d_out;

  u16*   xb    = (u16*)d_ws;                        // 4096*1024 bf16
  u16*   wqkvb = xb    + (size_t)4096 * 1024;       // 3072*1024 bf16
  u16*   woutb = wqkvb + (size_t)3072 * 1024;       // 1024*1024 bf16
  u16*   qkvb  = woutb + (size_t)1024 * 1024;       // 4096*3072 bf16
  u16*   attnb = qkvb  + (size_t)4096 * 3072;       // 4096*1024 bf16
  u16*   vtb   = attnb + (size_t)4096 * 1024;       // 4M f16 (V^T fragments)
  u16*   opart = vtb   + (size_t)4096 * 1024;       // 2*512*128*64 f16
  float* lpart = (float*)(opart + (size_t)2 * 512 * 128 * 64);  // 2*512*128 f32

  const float C2 = 0.03125f * 1.44269504088896340736f;  // dim^-0.5 * log2(e)

  cvt_bf16<<<4096 * 1024 / 4 / 256, 256, 0, stream>>>(x,     xb,    4096 * 1024 / 4, 0, 1.0f);
  cvt_bf16<<<3072 * 1024 / 4 / 256, 256, 0, stream>>>(w_qkv, wqkvb, 3072 * 1024 / 4,
                                                      1024 * 1024 / 4, C2);
  cvt_bf16<<<1024 * 1024 / 4 / 256, 256, 0, stream>>>(w_out, woutb, 1024 * 1024 / 4, 0, 1.0f);

  gemm_bt<<<dim3(24, 32), 256, 0, stream>>>(xb, wqkvb, qkvb, nullptr, 4096, 3072, 1024, 1);
  vt_kernel<<<dim3(32, 16), 256, 0, stream>>>(qkvb, vtb);
  attn<<<dim3(32, 16, 2), 256, 0, stream>>>(qkvb, vtb, opart, lpart);
  combine<<<dim3(32, 16), 256, 0, stream>>>(opart, lpart, attnb);
  gemm_bt<<<dim3(8, 32), 256, 0, stream>>>(attnb, woutb, outp, b_out, 4096, 1024, 1024, 0);
}